// Round 5
// baseline (243.229 us; speedup 1.0000x reference)
//
#include <hip/hip_runtime.h>
#include <stdint.h>

// Problem constants
#define B_      4
#define C_      3
#define H_      1024
#define W_      1024
#define OH_     31          // (1024-64)/32 + 1
#define NHS_    64          // 16-row half-strips per image
#define NP_     3844        // B * OH * OH
#define NPOSPB_ 961         // OH*OH
#define EPS_    1e-5f

// ws layout (float offsets)
#define TILE_PLANE 24576    // 12 bc * 64 hs * 32 tx
#define OFF_TILE  0         // 4 planes * 24576 = 98304
#define OFF_SC1   98304     // 32
#define OFF_SH1   98336     // 32
#define OFF_SC2   98368     // 32
#define OFF_SH2   98400     // 32
#define OFF_MX    98432     // 3 * 3844
#define OFF_MY    109964    // 3 * 3844
#define OFF_Y1    121496    // 3844 * 32 (AoS: [px][ch])
#define OFF_Y2    244504    // 3844 * 32 (AoS)
#define OFF_A     367512    // 3 * 3844
#define OFF_BV    379044    // 3 * 3844   (end 390576 floats = 1.56 MB)

typedef float f4 __attribute__((ext_vector_type(4)));

// ---------------- K1: 16-row half-strip partial sums of g, s, g*s, g*g per 32-col tile ----------------
// grid = (B*C)*64 = 768 blocks, 256 threads.
__global__ __launch_bounds__(256) void k1_tilesums(
        const float* __restrict__ g,
        const float* __restrict__ s,
        float* __restrict__ ws) {
    int blk = blockIdx.x;
    int bc = blk >> 6;        // 0..11
    int hs = blk & 63;        // half-strip (16 rows)
    int t  = threadIdx.x;     // covers columns [4t, 4t+4)
    const f4* gp = (const f4*)(g + ((size_t)bc * H_ + (size_t)hs * 16) * W_);
    const f4* sp = (const f4*)(s + ((size_t)bc * H_ + (size_t)hs * 16) * W_);
    float sg = 0.f, ss = 0.f, sgs = 0.f, sgg = 0.f;
#pragma unroll 4
    for (int r = 0; r < 16; r++) {
        f4 gv = gp[r * (W_ / 4) + t];
        f4 sv = __builtin_nontemporal_load(sp + r * (W_ / 4) + t);  // src read exactly once
        sg  += (gv.x + gv.y) + (gv.z + gv.w);
        ss  += (sv.x + sv.y) + (sv.z + sv.w);
        sgs += gv.x * sv.x + gv.y * sv.y + gv.z * sv.z + gv.w * sv.w;
        sgg += gv.x * gv.x + gv.y * gv.y + gv.z * gv.z + gv.w * gv.w;
    }
#pragma unroll
    for (int off = 4; off; off >>= 1) {
        sg  += __shfl_down(sg,  off, 8);
        ss  += __shfl_down(ss,  off, 8);
        sgs += __shfl_down(sgs, off, 8);
        sgg += __shfl_down(sgg, off, 8);
    }
    if ((t & 7) == 0) {
        int tx = t >> 3;
        int base = (bc * NHS_ + hs) * 32 + tx;
        ws[OFF_TILE + 0 * TILE_PLANE + base] = sg;
        ws[OFF_TILE + 1 * TILE_PLANE + base] = ss;
        ws[OFF_TILE + 2 * TILE_PLANE + base] = sgs;
        ws[OFF_TILE + 3 * TILE_PLANE + base] = sgg;
    }
}

// ---------------- K2: box sums -> h(cov,var) -> conv1 -> Y1 (AoS) ----------------
// thread = (px, 8-out-ch group); grid = 61 blocks * 256 (15616 >= 3844*4)
__global__ __launch_bounds__(256) void k2_conv1(
        const float* __restrict__ w1f,
        float* __restrict__ ws) {
    __shared__ float w[192];
    int t = threadIdx.x;
    if (t < 192) w[t] = w1f[t];
    __syncthreads();
    int pg = blockIdx.x * 256 + t;
    int px = pg >> 2;
    bool ok = px < NP_;
    int pp = ok ? px : NP_ - 1;
    int oq = (pg & 3) * 8;
    int b = pp / NPOSPB_;
    int r = pp % NPOSPB_;
    int oy = r / OH_, ox = r % OH_;
    float h[6];
#pragma unroll
    for (int c = 0; c < C_; c++) {
        int bc = b * 3 + c;
        int base = (bc * NHS_ + oy * 2) * 32 + ox;
        float S[4];
#pragma unroll
        for (int pl = 0; pl < 4; pl++) {
            const float* tp = ws + OFF_TILE + pl * TILE_PLANE + base;
            S[pl] = ((tp[0]  + tp[1])  + (tp[32] + tp[33]))
                  + ((tp[64] + tp[65]) + (tp[96] + tp[97]));
        }
        const float inv = 1.f / 4096.f;
        float mx = S[0] * inv, my = S[1] * inv;
        h[c]     = S[2] * inv - mx * my;   // cov
        h[3 + c] = S[3] * inv - mx * mx;   // var
        if (ok && oq == 0) { ws[OFF_MX + c * NP_ + pp] = mx; ws[OFF_MY + c * NP_ + pp] = my; }
    }
    float y[8];
#pragma unroll
    for (int j = 0; j < 8; j++) {
        int o = oq + j;
        float acc = 0.f;
#pragma unroll
        for (int i = 0; i < 6; i++) acc += w[o * 6 + i] * h[i];
        y[j] = acc;
    }
    if (ok) {
        f4* yp = (f4*)(ws + OFF_Y1 + pp * 32 + oq);
        f4 v0; v0.x = y[0]; v0.y = y[1]; v0.z = y[2]; v0.w = y[3];
        f4 v1; v1.x = y[4]; v1.y = y[5]; v1.z = y[6]; v1.w = y[7];
        yp[0] = v0; yp[1] = v1;
    }
}

// ---------------- kstats: batch mean/var over [NP][32] AoS -> BN scale/shift ----------------
// single block, 1024 threads = 32 px-lanes x 32 ch
__global__ __launch_bounds__(1024) void kstats(
        const float* __restrict__ yb,
        const float* __restrict__ gamma,
        const float* __restrict__ beta,
        float* __restrict__ sc_out,
        float* __restrict__ sh_out) {
    __shared__ float ls[32 * 33], lq[32 * 33];
    int t = threadIdx.x;
    int c = t & 31, pl = t >> 5;
    float s = 0.f, q = 0.f;
    for (int px = pl; px < NP_; px += 32) {
        float y = yb[px * 32 + c];
        s += y; q += y * y;
    }
    ls[pl * 33 + c] = s; lq[pl * 33 + c] = q;
    __syncthreads();
    if (t < 32) {
        float S = 0.f, Q = 0.f;
#pragma unroll
        for (int i = 0; i < 32; i++) { S += ls[i * 33 + t]; Q += lq[i * 33 + t]; }
        float m = S * (1.f / NP_);
        float v = Q * (1.f / NP_) - m * m;
        float sc = gamma[t] * rsqrtf(v + EPS_);
        sc_out[t] = sc;
        sh_out[t] = beta[t] - m * sc;
    }
}

// ---------------- K3: BN1+ReLU -> conv2 -> Y2 (AoS) ----------------
// thread = (px, 8-out-ch group); grid = 61 blocks * 256
__global__ __launch_bounds__(256) void k3_conv2(
        const float* __restrict__ w2f,
        float* __restrict__ ws) {
    __shared__ float w[1024];
    __shared__ float sc[32], sh[32];
    int t = threadIdx.x;
    for (int i = t; i < 1024; i += 256) w[i] = w2f[i];
    if (t < 32) { sc[t] = ws[OFF_SC1 + t]; sh[t] = ws[OFF_SH1 + t]; }
    __syncthreads();
    int pg = blockIdx.x * 256 + t;
    int px = pg >> 2;
    bool ok = px < NP_;
    int pp = ok ? px : NP_ - 1;
    int oq = (pg & 3) * 8;
    const f4* zp = (const f4*)(ws + OFF_Y1 + pp * 32);
    float z[32];
#pragma unroll
    for (int v4 = 0; v4 < 8; v4++) {
        f4 zv = zp[v4];
        z[v4 * 4 + 0] = fmaxf(zv.x * sc[v4 * 4 + 0] + sh[v4 * 4 + 0], 0.f);
        z[v4 * 4 + 1] = fmaxf(zv.y * sc[v4 * 4 + 1] + sh[v4 * 4 + 1], 0.f);
        z[v4 * 4 + 2] = fmaxf(zv.z * sc[v4 * 4 + 2] + sh[v4 * 4 + 2], 0.f);
        z[v4 * 4 + 3] = fmaxf(zv.w * sc[v4 * 4 + 3] + sh[v4 * 4 + 3], 0.f);
    }
    float y[8];
#pragma unroll
    for (int j = 0; j < 8; j++) {
        int o = oq + j;
        float acc = 0.f;
#pragma unroll
        for (int i = 0; i < 32; i++) acc += w[o * 32 + i] * z[i];
        y[j] = acc;
    }
    if (ok) {
        f4* yp = (f4*)(ws + OFF_Y2 + pp * 32 + oq);
        f4 v0; v0.x = y[0]; v0.y = y[1]; v0.z = y[2]; v0.w = y[3];
        f4 v1; v1.x = y[4]; v1.y = y[5]; v1.z = y[6]; v1.w = y[7];
        yp[0] = v0; yp[1] = v1;
    }
}

// ---------------- K4: BN2+ReLU -> conv3 -> A, b (SoA planes) ----------------
// grid = 61 blocks * 64 threads, thread = px
__global__ __launch_bounds__(64) void k4_conv3(
        const float* __restrict__ w3f,
        float* __restrict__ ws) {
    __shared__ float w[96];
    __shared__ float sc[32], sh[32];
    int t = threadIdx.x;
    for (int i = t; i < 96; i += 64) w[i] = w3f[i];
    if (t < 32) { sc[t] = ws[OFF_SC2 + t]; sh[t] = ws[OFF_SH2 + t]; }
    __syncthreads();
    int px = blockIdx.x * 64 + t;
    if (px >= NP_) return;
    const f4* zp = (const f4*)(ws + OFF_Y2 + px * 32);
    float z[32];
#pragma unroll
    for (int v4 = 0; v4 < 8; v4++) {
        f4 zv = zp[v4];
        z[v4 * 4 + 0] = fmaxf(zv.x * sc[v4 * 4 + 0] + sh[v4 * 4 + 0], 0.f);
        z[v4 * 4 + 1] = fmaxf(zv.y * sc[v4 * 4 + 1] + sh[v4 * 4 + 1], 0.f);
        z[v4 * 4 + 2] = fmaxf(zv.z * sc[v4 * 4 + 2] + sh[v4 * 4 + 2], 0.f);
        z[v4 * 4 + 3] = fmaxf(zv.w * sc[v4 * 4 + 3] + sh[v4 * 4 + 3], 0.f);
    }
#pragma unroll
    for (int c = 0; c < 3; c++) {
        float a = 0.f;
#pragma unroll
        for (int i = 0; i < 32; i++) a += w[c * 32 + i] * z[i];
        float mx = ws[OFF_MX + c * NP_ + px];
        float my = ws[OFF_MY + c * NP_ + px];
        ws[OFF_A  + c * NP_ + px] = a;
        ws[OFF_BV + c * NP_ + px] = my - a * mx;
    }
}

// ---------------- K5: bilinear upsample (align_corners) + out = A*g + b ----------------
// grid = B*C*H blocks (one per output row), 256 threads (4 px each, 16B vec I/O)
__global__ __launch_bounds__(256) void k5_final(
        const float* __restrict__ g,
        const float* __restrict__ ws,
        float* __restrict__ out) {
    int blk = blockIdx.x;
    int y  = blk & 1023;
    int bc = blk >> 10;
    int b = bc / 3, c = bc % 3;
    float fy = (float)y * (30.f / 1023.f);
    int y0 = (int)fy;
    float wy = fy - (float)y0;
    int y1i = min(y0 + 1, 30);
    const float* A0 = ws + OFF_A  + c * NP_ + b * NPOSPB_ + y0  * OH_;
    const float* A1 = ws + OFF_A  + c * NP_ + b * NPOSPB_ + y1i * OH_;
    const float* B0 = ws + OFF_BV + c * NP_ + b * NPOSPB_ + y0  * OH_;
    const float* B1 = ws + OFF_BV + c * NP_ + b * NPOSPB_ + y1i * OH_;
    int t = threadIdx.x;
    size_t rowoff = ((size_t)bc * H_ + (size_t)y) * W_;
    const f4* gp = (const f4*)(g + rowoff);
    f4* op = (f4*)(out + rowoff);
    f4 gv = gp[t];
    float go[4] = { gv.x, gv.y, gv.z, gv.w };
    float r[4];
#pragma unroll
    for (int j = 0; j < 4; j++) {
        int x = t * 4 + j;
        float fx = (float)x * (30.f / 1023.f);
        int x0 = (int)fx;
        float wx = fx - (float)x0;
        int x1 = min(x0 + 1, 30);
        float a  = (A0[x0] * (1.f - wx) + A0[x1] * wx) * (1.f - wy)
                 + (A1[x0] * (1.f - wx) + A1[x1] * wx) * wy;
        float bb = (B0[x0] * (1.f - wx) + B0[x1] * wx) * (1.f - wy)
                 + (B1[x0] * (1.f - wx) + B1[x1] * wx) * wy;
        r[j] = a * go[j] + bb;
    }
    f4 ov;
    ov.x = r[0]; ov.y = r[1]; ov.z = r[2]; ov.w = r[3];
    __builtin_nontemporal_store(ov, op + t);   // out never re-read
}

extern "C" void kernel_launch(void* const* d_in, const int* in_sizes, int n_in,
                              void* d_out, int out_size, void* d_ws, size_t ws_size,
                              hipStream_t stream) {
    const float* guide = (const float*)d_in[0];
    const float* src   = (const float*)d_in[1];
    // d_in[2] = box_w (all ones) -- unused; N == 4096 everywhere (VALID padding)
    const float* w1 = (const float*)d_in[3];
    const float* g1 = (const float*)d_in[4];
    const float* b1 = (const float*)d_in[5];
    const float* w2 = (const float*)d_in[6];
    const float* g2 = (const float*)d_in[7];
    const float* b2 = (const float*)d_in[8];
    const float* w3 = (const float*)d_in[9];
    float* ws = (float*)d_ws;
    float* out = (float*)d_out;

    hipLaunchKernelGGL(k1_tilesums, dim3(B_ * C_ * NHS_), dim3(256), 0, stream, guide, src, ws);
    hipLaunchKernelGGL(k2_conv1,   dim3(61),  dim3(256),  0, stream, w1, ws);
    hipLaunchKernelGGL(kstats,     dim3(1),   dim3(1024), 0, stream,
                       ws + OFF_Y1, g1, b1, ws + OFF_SC1, ws + OFF_SH1);
    hipLaunchKernelGGL(k3_conv2,   dim3(61),  dim3(256),  0, stream, w2, ws);
    hipLaunchKernelGGL(kstats,     dim3(1),   dim3(1024), 0, stream,
                       ws + OFF_Y2, g2, b2, ws + OFF_SC2, ws + OFF_SH2);
    hipLaunchKernelGGL(k4_conv3,   dim3(61),  dim3(64),   0, stream, w3, ws);
    hipLaunchKernelGGL(k5_final,   dim3(B_ * C_ * H_), dim3(256), 0, stream, guide, ws, out);
}

// Round 6
// 237.083 us; speedup vs baseline: 1.0259x; 1.0259x over previous
//
#include <hip/hip_runtime.h>
#include <stdint.h>

// Problem constants
#define B_      4
#define C_      3
#define H_      1024
#define W_      1024
#define OH_     31          // (1024-64)/32 + 1
#define NHS_    64          // 16-row half-strips per image
#define NP_     3844        // B * OH * OH
#define NPOSPB_ 961         // OH*OH
#define EPS_    1e-5f

// ws layout (float offsets)
#define TILE_PLANE 24576    // 12 bc * 64 hs * 32 tx
#define OFF_TILE  0         // 4 planes * 24576 = 98304
#define OFF_MX    98432     // 3 * 3844
#define OFF_MY    109964    // 3 * 3844
#define OFF_Y1    121496    // 3844 * 32 (AoS: [px][ch])
#define OFF_Y2    244504    // 3844 * 32 (AoS)
#define OFF_A     367512    // 3 * 3844
#define OFF_BV    379044    // 3 * 3844   (end 390576 floats = 1.56 MB)

typedef float f4 __attribute__((ext_vector_type(4)));

// ---------------- K1: 16-row half-strip partial sums of g, s, g*s, g*g per 32-col tile ----------------
// grid = (B*C)*64 = 768 blocks (3/CU), 256 threads.
__global__ __launch_bounds__(256) void k1_tilesums(
        const float* __restrict__ g,
        const float* __restrict__ s,
        float* __restrict__ ws) {
    int blk = blockIdx.x;
    int bc = blk >> 6;        // 0..11
    int hs = blk & 63;        // half-strip (16 rows)
    int t  = threadIdx.x;     // covers columns [4t, 4t+4)
    const f4* gp = (const f4*)(g + ((size_t)bc * H_ + (size_t)hs * 16) * W_);
    const f4* sp = (const f4*)(s + ((size_t)bc * H_ + (size_t)hs * 16) * W_);
    float sg = 0.f, ss = 0.f, sgs = 0.f, sgg = 0.f;
#pragma unroll 4
    for (int r = 0; r < 16; r++) {
        f4 gv = gp[r * (W_ / 4) + t];
        f4 sv = __builtin_nontemporal_load(sp + r * (W_ / 4) + t);  // src read exactly once
        sg  += (gv.x + gv.y) + (gv.z + gv.w);
        ss  += (sv.x + sv.y) + (sv.z + sv.w);
        sgs += gv.x * sv.x + gv.y * sv.y + gv.z * sv.z + gv.w * sv.w;
        sgg += gv.x * gv.x + gv.y * gv.y + gv.z * gv.z + gv.w * gv.w;
    }
#pragma unroll
    for (int off = 4; off; off >>= 1) {
        sg  += __shfl_down(sg,  off, 8);
        ss  += __shfl_down(ss,  off, 8);
        sgs += __shfl_down(sgs, off, 8);
        sgg += __shfl_down(sgg, off, 8);
    }
    if ((t & 7) == 0) {
        int tx = t >> 3;
        int base = (bc * NHS_ + hs) * 32 + tx;
        ws[OFF_TILE + 0 * TILE_PLANE + base] = sg;
        ws[OFF_TILE + 1 * TILE_PLANE + base] = ss;
        ws[OFF_TILE + 2 * TILE_PLANE + base] = sgs;
        ws[OFF_TILE + 3 * TILE_PLANE + base] = sgg;
    }
}

// ---------------- K2: box sums -> h(cov,var) -> conv1 -> Y1 (AoS) ----------------
// thread = (px, 8-out-ch group); grid = 61 blocks * 256 (15616 >= 3844*4)
__global__ __launch_bounds__(256) void k2_conv1(
        const float* __restrict__ w1f,
        float* __restrict__ ws) {
    __shared__ float w[192];
    int t = threadIdx.x;
    if (t < 192) w[t] = w1f[t];
    __syncthreads();
    int pg = blockIdx.x * 256 + t;
    int px = pg >> 2;
    bool ok = px < NP_;
    int pp = ok ? px : NP_ - 1;
    int oq = (pg & 3) * 8;
    int b = pp / NPOSPB_;
    int r = pp % NPOSPB_;
    int oy = r / OH_, ox = r % OH_;
    float h[6];
#pragma unroll
    for (int c = 0; c < C_; c++) {
        int bc = b * 3 + c;
        int base = (bc * NHS_ + oy * 2) * 32 + ox;
        float S[4];
#pragma unroll
        for (int pl = 0; pl < 4; pl++) {
            const float* tp = ws + OFF_TILE + pl * TILE_PLANE + base;
            S[pl] = ((tp[0]  + tp[1])  + (tp[32] + tp[33]))
                  + ((tp[64] + tp[65]) + (tp[96] + tp[97]));
        }
        const float inv = 1.f / 4096.f;
        float mx = S[0] * inv, my = S[1] * inv;
        h[c]     = S[2] * inv - mx * my;   // cov
        h[3 + c] = S[3] * inv - mx * mx;   // var
        if (ok && oq == 0) { ws[OFF_MX + c * NP_ + pp] = mx; ws[OFF_MY + c * NP_ + pp] = my; }
    }
    float y[8];
#pragma unroll
    for (int j = 0; j < 8; j++) {
        int o = oq + j;
        float acc = 0.f;
#pragma unroll
        for (int i = 0; i < 6; i++) acc += w[o * 6 + i] * h[i];
        y[j] = acc;
    }
    if (ok) {
        f4* yp = (f4*)(ws + OFF_Y1 + pp * 32 + oq);
        f4 v0; v0.x = y[0]; v0.y = y[1]; v0.z = y[2]; v0.w = y[3];
        f4 v1; v1.x = y[4]; v1.y = y[5]; v1.z = y[6]; v1.w = y[7];
        yp[0] = v0; yp[1] = v1;
    }
}

// ---- shared helper: per-block BN stats over AoS [NP][32] -> sc/sh in LDS ----
// 256 threads: c4 = t&7 (f4 channel group), pl = t>>3 (32 px lanes)
__device__ __forceinline__ void block_bn_stats(
        const float* __restrict__ yb,
        const float* __restrict__ gamma,
        const float* __restrict__ beta,
        float* ls, float* lq, float* sc, float* sh, int t) {
    int c4 = t & 7, pl = t >> 3;
    f4 s4 = {0.f, 0.f, 0.f, 0.f}, q4 = {0.f, 0.f, 0.f, 0.f};
    const f4* yp = (const f4*)yb;
    for (int px = pl; px < NP_; px += 32) {
        f4 v = yp[px * 8 + c4];
        s4 += v; q4 += v * v;
    }
    ls[pl * 33 + c4 * 4 + 0] = s4.x; lq[pl * 33 + c4 * 4 + 0] = q4.x;
    ls[pl * 33 + c4 * 4 + 1] = s4.y; lq[pl * 33 + c4 * 4 + 1] = q4.y;
    ls[pl * 33 + c4 * 4 + 2] = s4.z; lq[pl * 33 + c4 * 4 + 2] = q4.z;
    ls[pl * 33 + c4 * 4 + 3] = s4.w; lq[pl * 33 + c4 * 4 + 3] = q4.w;
    __syncthreads();
    if (t < 32) {
        float S = 0.f, Q = 0.f;
#pragma unroll
        for (int i = 0; i < 32; i++) { S += ls[i * 33 + t]; Q += lq[i * 33 + t]; }
        float m = S * (1.f / NP_);
        float v = Q * (1.f / NP_) - m * m;
        float scale = gamma[t] * rsqrtf(v + EPS_);
        sc[t] = scale; sh[t] = beta[t] - m * scale;
    }
    __syncthreads();
}

// ---------------- K3: per-block stats1 -> BN1+ReLU -> conv2 -> Y2 (AoS) ----------------
// thread = (px, 8-out-ch group); grid = 61 blocks * 256
__global__ __launch_bounds__(256) void k3_conv2(
        const float* __restrict__ w2f,
        const float* __restrict__ g1f,
        const float* __restrict__ b1f,
        float* __restrict__ ws) {
    __shared__ float w[1024];
    __shared__ float ls[32 * 33], lq[32 * 33];
    __shared__ float sc[32], sh[32];
    int t = threadIdx.x;
    for (int i = t; i < 1024; i += 256) w[i] = w2f[i];
    block_bn_stats(ws + OFF_Y1, g1f, b1f, ls, lq, sc, sh, t);
    int pg = blockIdx.x * 256 + t;
    int px = pg >> 2;
    bool ok = px < NP_;
    int pp = ok ? px : NP_ - 1;
    int oq = (pg & 3) * 8;
    const f4* zp = (const f4*)(ws + OFF_Y1 + pp * 32);
    float z[32];
#pragma unroll
    for (int v4 = 0; v4 < 8; v4++) {
        f4 zv = zp[v4];
        z[v4 * 4 + 0] = fmaxf(zv.x * sc[v4 * 4 + 0] + sh[v4 * 4 + 0], 0.f);
        z[v4 * 4 + 1] = fmaxf(zv.y * sc[v4 * 4 + 1] + sh[v4 * 4 + 1], 0.f);
        z[v4 * 4 + 2] = fmaxf(zv.z * sc[v4 * 4 + 2] + sh[v4 * 4 + 2], 0.f);
        z[v4 * 4 + 3] = fmaxf(zv.w * sc[v4 * 4 + 3] + sh[v4 * 4 + 3], 0.f);
    }
    float y[8];
#pragma unroll
    for (int j = 0; j < 8; j++) {
        int o = oq + j;
        float acc = 0.f;
#pragma unroll
        for (int i = 0; i < 32; i++) acc += w[o * 32 + i] * z[i];
        y[j] = acc;
    }
    if (ok) {
        f4* yp = (f4*)(ws + OFF_Y2 + pp * 32 + oq);
        f4 v0; v0.x = y[0]; v0.y = y[1]; v0.z = y[2]; v0.w = y[3];
        f4 v1; v1.x = y[4]; v1.y = y[5]; v1.z = y[6]; v1.w = y[7];
        yp[0] = v0; yp[1] = v1;
    }
}

// ---------------- K4: per-block stats2 -> BN2+ReLU -> conv3 -> A, b (SoA planes) ----------------
// grid = 61 blocks * 256; conv part: t<192, thread = (px, out-c)
__global__ __launch_bounds__(256) void k4_conv3(
        const float* __restrict__ w3f,
        const float* __restrict__ g2f,
        const float* __restrict__ b2f,
        float* __restrict__ ws) {
    __shared__ float w[96];
    __shared__ float ls[32 * 33], lq[32 * 33];
    __shared__ float sc[32], sh[32];
    int t = threadIdx.x;
    if (t < 96) w[t] = w3f[t];
    block_bn_stats(ws + OFF_Y2, g2f, b2f, ls, lq, sc, sh, t);
    if (t >= 192) return;
    int q3 = t / 3;            // px lane 0..63
    int c  = t - 3 * q3;       // out channel 0..2
    int px = blockIdx.x * 64 + q3;
    if (px >= NP_) return;
    const f4* zp = (const f4*)(ws + OFF_Y2 + px * 32);
    float a = 0.f;
#pragma unroll
    for (int v4 = 0; v4 < 8; v4++) {
        f4 zv = zp[v4];
        a += w[c * 32 + v4 * 4 + 0] * fmaxf(zv.x * sc[v4 * 4 + 0] + sh[v4 * 4 + 0], 0.f);
        a += w[c * 32 + v4 * 4 + 1] * fmaxf(zv.y * sc[v4 * 4 + 1] + sh[v4 * 4 + 1], 0.f);
        a += w[c * 32 + v4 * 4 + 2] * fmaxf(zv.z * sc[v4 * 4 + 2] + sh[v4 * 4 + 2], 0.f);
        a += w[c * 32 + v4 * 4 + 3] * fmaxf(zv.w * sc[v4 * 4 + 3] + sh[v4 * 4 + 3], 0.f);
    }
    float mx = ws[OFF_MX + c * NP_ + px];
    float my = ws[OFF_MY + c * NP_ + px];
    ws[OFF_A  + c * NP_ + px] = a;
    ws[OFF_BV + c * NP_ + px] = my - a * mx;
}

// ---------------- K5: bilinear upsample (align_corners) + out = A*g + b ----------------
// grid = B*C*H blocks (one per output row), 256 threads (4 px each, 16B vec I/O)
__global__ __launch_bounds__(256) void k5_final(
        const float* __restrict__ g,
        const float* __restrict__ ws,
        float* __restrict__ out) {
    int blk = blockIdx.x;
    int y  = blk & 1023;
    int bc = blk >> 10;
    int b = bc / 3, c = bc % 3;
    float fy = (float)y * (30.f / 1023.f);
    int y0 = (int)fy;
    float wy = fy - (float)y0;
    int y1i = min(y0 + 1, 30);
    const float* A0 = ws + OFF_A  + c * NP_ + b * NPOSPB_ + y0  * OH_;
    const float* A1 = ws + OFF_A  + c * NP_ + b * NPOSPB_ + y1i * OH_;
    const float* B0 = ws + OFF_BV + c * NP_ + b * NPOSPB_ + y0  * OH_;
    const float* B1 = ws + OFF_BV + c * NP_ + b * NPOSPB_ + y1i * OH_;
    int t = threadIdx.x;
    size_t rowoff = ((size_t)bc * H_ + (size_t)y) * W_;
    const f4* gp = (const f4*)(g + rowoff);
    f4* op = (f4*)(out + rowoff);
    f4 gv = gp[t];
    float go[4] = { gv.x, gv.y, gv.z, gv.w };
    float r[4];
#pragma unroll
    for (int j = 0; j < 4; j++) {
        int x = t * 4 + j;
        float fx = (float)x * (30.f / 1023.f);
        int x0 = (int)fx;
        float wx = fx - (float)x0;
        int x1 = min(x0 + 1, 30);
        float a  = (A0[x0] * (1.f - wx) + A0[x1] * wx) * (1.f - wy)
                 + (A1[x0] * (1.f - wx) + A1[x1] * wx) * wy;
        float bb = (B0[x0] * (1.f - wx) + B0[x1] * wx) * (1.f - wy)
                 + (B1[x0] * (1.f - wx) + B1[x1] * wx) * wy;
        r[j] = a * go[j] + bb;
    }
    f4 ov;
    ov.x = r[0]; ov.y = r[1]; ov.z = r[2]; ov.w = r[3];
    __builtin_nontemporal_store(ov, op + t);   // out never re-read
}

extern "C" void kernel_launch(void* const* d_in, const int* in_sizes, int n_in,
                              void* d_out, int out_size, void* d_ws, size_t ws_size,
                              hipStream_t stream) {
    const float* guide = (const float*)d_in[0];
    const float* src   = (const float*)d_in[1];
    // d_in[2] = box_w (all ones) -- unused; N == 4096 everywhere (VALID padding)
    const float* w1 = (const float*)d_in[3];
    const float* g1 = (const float*)d_in[4];
    const float* b1 = (const float*)d_in[5];
    const float* w2 = (const float*)d_in[6];
    const float* g2 = (const float*)d_in[7];
    const float* b2 = (const float*)d_in[8];
    const float* w3 = (const float*)d_in[9];
    float* ws = (float*)d_ws;
    float* out = (float*)d_out;

    hipLaunchKernelGGL(k1_tilesums, dim3(B_ * C_ * NHS_), dim3(256), 0, stream, guide, src, ws);
    hipLaunchKernelGGL(k2_conv1,   dim3(61),  dim3(256), 0, stream, w1, ws);
    hipLaunchKernelGGL(k3_conv2,   dim3(61),  dim3(256), 0, stream, w2, g1, b1, ws);
    hipLaunchKernelGGL(k4_conv3,   dim3(61),  dim3(256), 0, stream, w3, g2, b2, ws);
    hipLaunchKernelGGL(k5_final,   dim3(B_ * C_ * H_), dim3(256), 0, stream, guide, ws, out);
}